// Round 8
// baseline (306.228 us; speedup 1.0000x reference)
//
#include <hip/hip_runtime.h>

#define B_ 8
#define NH 12
#define NTOK 1025
#define FT 768
#define MROWS (B_*NTOK)      // 8200
#define NPAD2 1088           // token pad for attention (34*32)
#define CH2 34               // 32-token chunks
#define NQT 36               // 32-row Q tiles
#define NTT 34               // 32-token bias tiles
#define NRT18 18             // 64-row attn blocks
#define LOG2E 1.44269504089f

typedef __bf16 bf16x8 __attribute__((ext_vector_type(8)));
typedef __bf16 bf16x2 __attribute__((ext_vector_type(2)));
typedef float floatx4 __attribute__((ext_vector_type(4)));
typedef float floatx16 __attribute__((ext_vector_type(16)));
typedef int intx4 __attribute__((ext_vector_type(4)));

// async global->LDS, 16B/lane; LDS dst wave-uniform, HW scatters +lane*16.
__device__ __forceinline__ void async_ld16(const void* gp, void* lp) {
  __builtin_amdgcn_global_load_lds(
      (const __attribute__((address_space(1))) void*)gp,
      (__attribute__((address_space(3))) void*)lp, 16, 0, 0);
}

// ---------------- combined fp32 -> bf16 convert (tokens, qkvw, projw) ----------------
__global__ __launch_bounds__(256) void cvt3_bf16(
    const float* __restrict__ s0, __bf16* __restrict__ d0, int n0,
    const float* __restrict__ s1, __bf16* __restrict__ d1, int n1,
    const float* __restrict__ s2, __bf16* __restrict__ d2, int n2) {
  int i = blockIdx.x * 256 + threadIdx.x;
  const float* s; __bf16* d;
  if (i < n0) { s = s0; d = d0; }
  else if (i < n0 + n1) { i -= n0; s = s1; d = d1; }
  else { i -= n0 + n1; if (i >= n2) return; s = s2; d = d2; }
  float4 v = ((const float4*)s)[i];
  __bf16 o[4] = {(__bf16)v.x, (__bf16)v.y, (__bf16)v.z, (__bf16)v.w};
  *(uint2*)(d + 4 * (size_t)i) = *(uint2*)o;
}

// ---------------- relpos bias gather into 32x32 S^T C-fragment tiles ----------------
// Bb[h][qt][tt][lane*16+j]: bias[qrow=qt*32+(lane&31)][token=tt*32+(j&3)+8*(j>>2)+4*(lane>>5)]
// values pre-scaled by log2(e) (softmax uses exp2). pad tokens -> -1e30 mask.
__global__ __launch_bounds__(256) void bias_gather_t(
    const int* __restrict__ idx, const float* __restrict__ table,
    __bf16* __restrict__ Bb) {
  const int qt = blockIdx.x, tt = blockIdx.y;
  const int t = threadIdx.x;
  const int lane = t & 63, w = t >> 6;
  const int l31 = lane & 31, hb = lane >> 5;
  int qrow = qt * 32 + l31; if (qrow > NTOK - 1) qrow = NTOK - 1;
  int ids[16]; bool ok[16];
#pragma unroll
  for (int j = 0; j < 16; ++j) {
    const int token = tt * 32 + (j & 3) + 8 * (j >> 2) + 4 * hb;
    ok[j] = token < NTOK;
    ids[j] = ok[j] ? idx[qrow * NTOK + token] : 0;
  }
#pragma unroll
  for (int g = 0; g < 3; ++g) {
    const int h = w + g * 4;
    __bf16 v[16];
#pragma unroll
    for (int j = 0; j < 16; ++j)
      v[j] = ok[j] ? (__bf16)(table[ids[j] * NH + h] * LOG2E) : (__bf16)(-1e30f);
    uint4* dst = (uint4*)(Bb + (((size_t)h * NQT + qt) * NTT + tt) * 1024 + lane * 16);
    dst[0] = ((uint4*)v)[0];
    dst[1] = ((uint4*)v)[1];
  }
}

// ---------------- 128x128 GEMM core v2: A direct-from-L2, B LDS-staged ----------------
// A-fragments are per-lane contiguous 16B global loads (register double-buffered,
// depth 1). B staged via global_load_lds into 3 rotating 8KB buffers (12KB LDS total).
// Per iter: issue B(k+1) [2 ops] + load A(k+1) [4 ops]; s_waitcnt vmcnt(6) leaves only
// those 6 outstanding -> A(k) regs + B(k) LDS ready. Race: writing buf (k+1)%3 while
// slowest wave (past barrier k-1) reads (k-1)%3: distance 2 mod 3, safe.
__device__ __forceinline__ void gemm128_ad(
    const __bf16* __restrict__ A, const __bf16* __restrict__ W,
    int m0, int n0, int M, __bf16* Bt, floatx4 acc[4][4]) {
  const int tid = threadIdx.x, wave = tid >> 6, lane = tid & 63;
  const int l = lane & 15, qd = lane >> 4;
  const int wr = wave >> 1, wc = wave & 1;
  // B staging: each wave stages 32 rows (2KB = 2 async_ld16)
  const int srow = lane >> 2, sg = lane & 3;
  const int r0 = wave * 32 + srow, r1 = r0 + 16;
  const int sw0 = (sg ^ (r0 & 3)) * 8;          // staging XOR swizzle (row&3)
  const __bf16* gB0 = W + (size_t)(n0 + r0) * FT + sw0;
  const __bf16* gB1 = W + (size_t)(n0 + r1) * FT + sw0;
  const int woff = wave * 1024;
  const int fsw = (qd ^ (l & 3)) * 8;           // fragment-read swizzle
  // A fragment base pointers (4 per wave), row-clamped
  const __bf16* gA[4];
#pragma unroll
  for (int t = 0; t < 4; ++t) {
    int gm = m0 + wr * 64 + t * 16 + l;
    if (gm >= M) gm = M - 1;
    gA[t] = A + (size_t)gm * FT + qd * 8;
  }

  bf16x8 aF[4], aN[4];
#pragma unroll
  for (int t = 0; t < 4; ++t) aF[t] = *(const bf16x8*)(gA[t]);
  {
    __bf16* b = Bt + woff;
    async_ld16(gB0, b);
    async_ld16(gB1, b + 512);
  }

  int bk = 0;
  for (int k = 0; k < 23; ++k) {               // FT/32 - 1 = 23
    int bn = bk + 1; if (bn == 3) bn = 0;
    {
      __bf16* b = Bt + bn * 4096 + woff;
      async_ld16(gB0 + (k + 1) * 32, b);
      async_ld16(gB1 + (k + 1) * 32, b + 512);
    }
#pragma unroll
    for (int t = 0; t < 4; ++t) aN[t] = *(const bf16x8*)(gA[t] + (k + 1) * 32);
    __builtin_amdgcn_s_waitcnt(0x0F76);        // vmcnt(6): only this iter's issues out
    __builtin_amdgcn_s_barrier();
    {
      const __bf16* bb = Bt + bk * 4096;
      bf16x8 bF[4];
#pragma unroll
      for (int u = 0; u < 4; ++u)
        bF[u] = *(const bf16x8*)(bb + (wc * 64 + u * 16 + l) * 32 + fsw);
#pragma unroll
      for (int t = 0; t < 4; ++t)
#pragma unroll
        for (int u = 0; u < 4; ++u)
          acc[t][u] = __builtin_amdgcn_mfma_f32_16x16x32_bf16(aF[t], bF[u], acc[t][u], 0, 0, 0);
    }
#pragma unroll
    for (int t = 0; t < 4; ++t) aF[t] = aN[t];
    bk = bn;
  }
  __builtin_amdgcn_s_waitcnt(0x0F70);          // vmcnt(0)
  __builtin_amdgcn_s_barrier();
  {
    const __bf16* bb = Bt + bk * 4096;
    bf16x8 bF[4];
#pragma unroll
    for (int u = 0; u < 4; ++u)
      bF[u] = *(const bf16x8*)(bb + (wc * 64 + u * 16 + l) * 32 + fsw);
#pragma unroll
    for (int t = 0; t < 4; ++t)
#pragma unroll
      for (int u = 0; u < 4; ++u)
        acc[t][u] = __builtin_amdgcn_mfma_f32_16x16x32_bf16(aF[t], bF[u], acc[t][u], 0, 0, 0);
  }
}

// ---------------- QKV projection GEMM + bias/scale epilogue ----------------
// Grid swizzle: xcd = u&7; m-tile = ((u>>3)/18)*8 + xcd; n fastest -> A-tile L2-hot.
// Q pre-scaled by 0.125*log2e.
__global__ __launch_bounds__(256) void qkv_gemm128(
    const __bf16* __restrict__ tokens, const __bf16* __restrict__ qkvw,
    const float* __restrict__ qbias, const float* __restrict__ vbias,
    __bf16* __restrict__ Qb, __bf16* __restrict__ Kc, __bf16* __restrict__ Vc) {
  __shared__ __bf16 Bt[3 * 4096];   // 24 KB
  const int u0 = blockIdx.x;
  const int c = u0 & 7, q0 = u0 >> 3;
  const int mi = (q0 / 18) * 8 + c, ni = q0 % 18;
  if (mi >= 65) return;
  const int m0 = mi * 128, n0 = ni * 128;
  const int tid = threadIdx.x, wave = tid >> 6, lane = tid & 63;
  const int l = lane & 15, qd = lane >> 4;
  const int wr = wave >> 1, wc = wave & 1;
  floatx4 acc[4][4];
#pragma unroll
  for (int t = 0; t < 4; ++t)
#pragma unroll
    for (int u = 0; u < 4; ++u) acc[t][u] = (floatx4){0.f, 0.f, 0.f, 0.f};
  gemm128_ad(tokens, qkvw, m0, n0, MROWS, Bt, acc);

  const int which = (n0 / FT);
  const int nrem0 = n0 - which * FT;
#pragma unroll
  for (int u = 0; u < 4; ++u) {
    const int rem = nrem0 + wc * 64 + u * 16 + l;
    const int h = rem >> 6, f = rem & 63;
    const float qb = (which == 0) ? qbias[h * 64 + f] : 0.f;
    const float vb = (which == 2) ? vbias[h * 64 + f] : 0.f;
#pragma unroll
    for (int t = 0; t < 4; ++t) {
#pragma unroll
      for (int r = 0; r < 4; ++r) {
        const int gm = m0 + wr * 64 + t * 16 + qd * 4 + r;
        if (gm >= MROWS) continue;
        const int b = gm / NTOK;
        const int tok = gm - b * NTOK;
        const size_t bh = (size_t)(b * NH + h);
        float v = acc[t][u][r];
        if (which == 0) {
          Qb[(bh * NPAD2 + tok) * 64 + f] = (__bf16)((v + qb) * (0.125f * LOG2E));
        } else if (which == 1) {
          // Kc 32-tok chunks: [bh][tok>>5][dg=f>>3][tok&31][f&7]
          const size_t e = ((size_t)(bh * CH2 + (tok >> 5))) * 2048 +
                           (((f >> 3) * 32 + (tok & 31)) << 3) + (f & 7);
          Kc[e] = (__bf16)v;
        } else {
          // Vc 32-tok chunks: [bh][tok>>5][tg=(tok>>3)&3][f][tok&7]
          const size_t e = ((size_t)(bh * CH2 + (tok >> 5))) * 2048 +
                           (((((tok >> 3) & 3) * 64 + f)) << 3) + (tok & 7);
          Vc[e] = (__bf16)(v + vb);
        }
      }
    }
  }
}

// ---------------- output projection GEMM + bias (fp32 out), same swizzle NB=6 ----------------
__global__ __launch_bounds__(256) void proj_gemm128(
    const __bf16* __restrict__ Ao, const __bf16* __restrict__ projw,
    const float* __restrict__ projb, float* __restrict__ out) {
  __shared__ __bf16 Bt[3 * 4096];
  const int u0 = blockIdx.x;
  const int c = u0 & 7, q0 = u0 >> 3;
  const int mi = (q0 / 6) * 8 + c, ni = q0 % 6;
  if (mi >= 65) return;
  const int m0 = mi * 128, n0 = ni * 128;
  const int tid = threadIdx.x, wave = tid >> 6, lane = tid & 63;
  const int l = lane & 15, qd = lane >> 4;
  const int wr = wave >> 1, wc = wave & 1;
  floatx4 acc[4][4];
#pragma unroll
  for (int t = 0; t < 4; ++t)
#pragma unroll
    for (int u = 0; u < 4; ++u) acc[t][u] = (floatx4){0.f, 0.f, 0.f, 0.f};
  gemm128_ad(Ao, projw, m0, n0, MROWS, Bt, acc);
#pragma unroll
  for (int u = 0; u < 4; ++u) {
    const int gn = n0 + wc * 64 + u * 16 + l;
    const float pb = projb[gn];
#pragma unroll
    for (int t = 0; t < 4; ++t)
#pragma unroll
      for (int r = 0; r < 4; ++r) {
        const int gm = m0 + wr * 64 + t * 16 + qd * 4 + r;
        if (gm < MROWS) out[(size_t)gm * FT + gn] = acc[t][u][r] + pb;
      }
  }
}

// ---------------- pipelined flash attention: 64 Q-rows / 2-wave block ----------------
// 32-token chunks; 3 rotating LDS buffer sets (wave0 stages K, wave1 stages V);
// bias prefetched to regs; raw s_barrier + vmcnt(6) keeps next chunk in flight.
// S^T = K.Q^T (32x32x16); P = exp2(S + bias') [log2e pre-folded]; O^T = V^T.P^T.
// Pad tokens carry bias -1e30 -> exp2()==0, so un-zeroed K/V pad garbage is inert.
__global__ __launch_bounds__(128) void attn_flash(
    const __bf16* __restrict__ Qb, const __bf16* __restrict__ Kc,
    const __bf16* __restrict__ Vc, const __bf16* __restrict__ Bb,
    __bf16* __restrict__ Ao) {
  __shared__ __bf16 Kl[3][2048], Vl[3][2048];   // 24 KB total
  const int bh = blockIdx.x;
  const int rt = blockIdx.y;
  const int h = bh % NH, b = bh / NH;
  const int wave = threadIdx.x >> 6, lane = threadIdx.x & 63;
  const int l31 = lane & 31, hb = lane >> 5;
  const int qt = rt * 2 + wave;
  int qrow = qt * 32 + l31; if (qrow > NTOK - 1) qrow = NTOK - 1;

  // Q fragments (B-operand): B[n=qrow=lane&31][k = dk*16 + hb*8 + i]
  bf16x8 qf[4];
  {
    const __bf16* Qp = Qb + ((size_t)bh * NPAD2 + qrow) * 64 + hb * 8;
#pragma unroll
    for (int d = 0; d < 4; ++d) qf[d] = *(const bf16x8*)(Qp + d * 16);
  }

  floatx16 o0, o1;
#pragma unroll
  for (int j = 0; j < 16; ++j) { o0[j] = 0.f; o1[j] = 0.f; }
  float lsum = 0.f;

  const __bf16* KVg = (wave ? Vc : Kc) + (size_t)bh * CH2 * 2048;
  const __bf16* Bg = Bb + ((size_t)h * NQT + qt) * NTT * 1024 + lane * 16;

  auto issue = [&](int c, int buf) {
    const __bf16* src = KVg + (size_t)c * 2048 + lane * 8;
    __bf16* dst = wave ? Vl[buf] : Kl[buf];
#pragma unroll
    for (int ii = 0; ii < 4; ++ii) async_ld16(src + ii * 512, dst + ii * 512);
  };

  issue(0, 0);
  bf16x8 bc0 = *(const bf16x8*)(Bg);
  bf16x8 bc1 = *(const bf16x8*)(Bg + 8);
  int buf = 0;
  for (int c = 0; c < CH2; ++c) {
    int nbuf = buf + 1; if (nbuf == 3) nbuf = 0;
    bf16x8 bn0 = bc0, bn1 = bc1;
    if (c + 1 < CH2) {
      issue(c + 1, nbuf);
      bn0 = *(const bf16x8*)(Bg + (size_t)(c + 1) * 1024);
      bn1 = *(const bf16x8*)(Bg + (size_t)(c + 1) * 1024 + 8);
      __builtin_amdgcn_s_waitcnt(0x0F76);   // vmcnt(6): chunk c landed, c+1 in flight
    } else {
      __builtin_amdgcn_s_waitcnt(0x0F70);   // vmcnt(0)
    }
    __builtin_amdgcn_s_barrier();

    // QK^T: S^T(32 tokens x 32 qrows)
    floatx16 st;
#pragma unroll
    for (int j = 0; j < 16; ++j) st[j] = 0.f;
#pragma unroll
    for (int dk = 0; dk < 4; ++dk) {
      bf16x8 a = *(const bf16x8*)(Kl[buf] + ((dk * 2 + hb) * 32 + l31) * 8);
      st = __builtin_amdgcn_mfma_f32_32x32x16_bf16(a, qf[dk], st, 0, 0, 0);
    }
    // P = exp2(S^T + bias'), accumulate l
    float e[16];
#pragma unroll
    for (int j = 0; j < 16; ++j) {
      const float bj = (float)(j < 8 ? bc0[j] : bc1[j - 8]);
      e[j] = __builtin_amdgcn_exp2f(st[j] + bj);
      lsum += e[j];
    }
    int pk[8];
#pragma unroll
    for (int j2 = 0; j2 < 8; ++j2) {
      bf16x2 pr = {(__bf16)e[2 * j2], (__bf16)e[2 * j2 + 1]};
      pk[j2] = __builtin_bit_cast(int, pr);
    }
    // PV: O^T += V^T . P^T (P^T B-frags via xor-32 exchange)
#pragma unroll
    for (int ks = 0; ks < 2; ++ks) {
      const int r01a = pk[4 * ks + 0], r01b = pk[4 * ks + 1];
      const int r23a = pk[4 * ks + 2], r23b = pk[4 * ks + 3];
      const int t01a = __shfl_xor(r01a, 32), t01b = __shfl_xor(r01b, 32);
      const int t23a = __shfl_xor(r23a, 32), t23b = __shfl_xor(r23b, 32);
      intx4 fi;
      fi[0] = hb ? t23a : r01a;
      fi[1] = hb ? t23b : r01b;
      fi[2] = hb ? r23a : t01a;
      fi[3] = hb ? r23b : t01b;
      bf16x8 pb = __builtin_bit_cast(bf16x8, fi);
      bf16x8 va0 = *(const bf16x8*)(Vl[buf] + ((ks * 2 + hb) * 64 + l31) * 8);
      bf16x8 va1 = *(const bf16x8*)(Vl[buf] + ((ks * 2 + hb) * 64 + 32 + l31) * 8);
      o0 = __builtin_amdgcn_mfma_f32_32x32x16_bf16(va0, pb, o0, 0, 0, 0);
      o1 = __builtin_amdgcn_mfma_f32_32x32x16_bf16(va1, pb, o1, 0, 0, 0);
    }
    bc0 = bn0; bc1 = bn1;
    buf = nbuf;
  }

  const float ltot = lsum + __shfl_xor(lsum, 32);
  const float rinv = 1.0f / ltot;
  const int tok = rt * 64 + wave * 32 + l31;
  if (tok < NTOK) {
    __bf16* op = Ao + ((size_t)b * NTOK + tok) * FT + h * 64;
#pragma unroll
    for (int ft = 0; ft < 2; ++ft) {
#pragma unroll
      for (int jg = 0; jg < 4; ++jg) {
        const int f = ft * 32 + jg * 8 + hb * 4;
        __bf16 v4[4];
#pragma unroll
        for (int q = 0; q < 4; ++q) {
          const float ov = ft ? o1[jg * 4 + q] : o0[jg * 4 + q];
          v4[q] = (__bf16)(ov * rinv);
        }
        *(uint2*)(op + f) = *(uint2*)v4;
      }
    }
  }
}

extern "C" void kernel_launch(void* const* d_in, const int* in_sizes, int n_in,
                              void* d_out, int out_size, void* d_ws, size_t ws_size,
                              hipStream_t stream) {
  (void)in_sizes; (void)n_in; (void)out_size; (void)ws_size;
  const float* tokens = (const float*)d_in[0];
  const float* qkvw   = (const float*)d_in[1];
  const float* qbias  = (const float*)d_in[2];
  const float* vbias  = (const float*)d_in[3];
  const float* table  = (const float*)d_in[4];
  const float* projw  = (const float*)d_in[5];
  const float* projb  = (const float*)d_in[6];
  const int*   rpidx  = (const int*)d_in[7];
  float* out = (float*)d_out;
  char* ws = (char*)d_ws;

  const size_t QB2 = (size_t)B_ * NH * NPAD2 * 64 * 2;        // 13,369,344 B
  const size_t BBT = (size_t)NH * NQT * NTT * 1024 * 2;       // 30,081,024 B
  const size_t AOB = (size_t)MROWS * FT * 2;                  // 12,595,200 B
  const size_t WQB = (size_t)3 * FT * FT * 2;
  __bf16* Qb = (__bf16*)(ws);
  __bf16* Kc = (__bf16*)(ws + QB2);
  __bf16* Vc = (__bf16*)(ws + 2 * QB2);
  __bf16* Bb = (__bf16*)(ws + 3 * QB2);
  __bf16* Tb = (__bf16*)(ws + 3 * QB2 + BBT);  // tokens bf16; Ao aliases (dead after qkv)
  __bf16* Ao = Tb;
  __bf16* Wq = (__bf16*)(ws + 3 * QB2 + BBT + AOB);
  __bf16* Wp = (__bf16*)(ws + 3 * QB2 + BBT + AOB + WQB);
  // total ~87.5 MB

  const int n0 = MROWS * FT / 4, n1 = 3 * FT * FT / 4, n2 = FT * FT / 4;
  cvt3_bf16<<<(n0 + n1 + n2 + 255) / 256, 256, 0, stream>>>(
      tokens, Tb, n0, qkvw, Wq, n1, projw, Wp, n2);
  bias_gather_t<<<dim3(NQT, NTT), 256, 0, stream>>>(rpidx, table, Bb);
  qkv_gemm128<<<8 * 9 * 18, 256, 0, stream>>>(Tb, Wq, qbias, vbias, Qb, Kc, Vc);
  attn_flash<<<dim3(B_ * NH, NRT18), 128, 0, stream>>>(Qb, Kc, Vc, Bb, Ao);
  proj_gemm128<<<8 * 9 * 6, 256, 0, stream>>>(Ao, Wp, projb, out);
}

// Round 9
// 289.358 us; speedup vs baseline: 1.0583x; 1.0583x over previous
//
#include <hip/hip_runtime.h>

#define B_ 8
#define NH 12
#define NTOK 1025
#define FT 768
#define MROWS (B_*NTOK)      // 8200
#define NPAD2 1088           // token pad for attention (34*32)
#define CH2 34               // 32-token chunks
#define NQT 36               // 32-row Q tiles
#define NTT 34               // 32-token bias tiles
#define NRT18 18             // 64-row attn blocks
#define LOG2E 1.44269504089f

typedef __bf16 bf16x8 __attribute__((ext_vector_type(8)));
typedef __bf16 bf16x2 __attribute__((ext_vector_type(2)));
typedef float floatx4 __attribute__((ext_vector_type(4)));
typedef float floatx16 __attribute__((ext_vector_type(16)));
typedef int intx4 __attribute__((ext_vector_type(4)));

// async global->LDS, 16B/lane; LDS dst wave-uniform, HW scatters +lane*16.
__device__ __forceinline__ void async_ld16(const void* gp, void* lp) {
  __builtin_amdgcn_global_load_lds(
      (const __attribute__((address_space(1))) void*)gp,
      (__attribute__((address_space(3))) void*)lp, 16, 0, 0);
}

// ---------------- combined fp32 -> bf16 convert (tokens, qkvw, projw) ----------------
__global__ __launch_bounds__(256) void cvt3_bf16(
    const float* __restrict__ s0, __bf16* __restrict__ d0, int n0,
    const float* __restrict__ s1, __bf16* __restrict__ d1, int n1,
    const float* __restrict__ s2, __bf16* __restrict__ d2, int n2) {
  int i = blockIdx.x * 256 + threadIdx.x;
  const float* s; __bf16* d;
  if (i < n0) { s = s0; d = d0; }
  else if (i < n0 + n1) { i -= n0; s = s1; d = d1; }
  else { i -= n0 + n1; if (i >= n2) return; s = s2; d = d2; }
  float4 v = ((const float4*)s)[i];
  __bf16 o[4] = {(__bf16)v.x, (__bf16)v.y, (__bf16)v.z, (__bf16)v.w};
  *(uint2*)(d + 4 * (size_t)i) = *(uint2*)o;
}

// ---------------- relpos bias gather into 32x32 S^T C-fragment tiles ----------------
// Bb[h][qt][tt][lane*16+j]: bias[qrow=qt*32+(lane&31)][token=tt*32+(j&3)+8*(j>>2)+4*(lane>>5)]
// values pre-scaled by log2(e) (softmax uses exp2). pad tokens -> -1e30 mask.
__global__ __launch_bounds__(256) void bias_gather_t(
    const int* __restrict__ idx, const float* __restrict__ table,
    __bf16* __restrict__ Bb) {
  const int qt = blockIdx.x, tt = blockIdx.y;
  const int t = threadIdx.x;
  const int lane = t & 63, w = t >> 6;
  const int l31 = lane & 31, hb = lane >> 5;
  int qrow = qt * 32 + l31; if (qrow > NTOK - 1) qrow = NTOK - 1;
  int ids[16]; bool ok[16];
#pragma unroll
  for (int j = 0; j < 16; ++j) {
    const int token = tt * 32 + (j & 3) + 8 * (j >> 2) + 4 * hb;
    ok[j] = token < NTOK;
    ids[j] = ok[j] ? idx[qrow * NTOK + token] : 0;
  }
#pragma unroll
  for (int g = 0; g < 3; ++g) {
    const int h = w + g * 4;
    __bf16 v[16];
#pragma unroll
    for (int j = 0; j < 16; ++j)
      v[j] = ok[j] ? (__bf16)(table[ids[j] * NH + h] * LOG2E) : (__bf16)(-1e30f);
    uint4* dst = (uint4*)(Bb + (((size_t)h * NQT + qt) * NTT + tt) * 1024 + lane * 16);
    dst[0] = ((uint4*)v)[0];
    dst[1] = ((uint4*)v)[1];
  }
}

// ---------------- 128x128 GEMM core: both operands LDS-staged, depth-2 prefetch ----------------
// 4 rotating buffer pairs (64 KB LDS). Each iter issues tile k+2 (4 async/wave) and
// waits vmcnt(8) -> tiles k+1,k+2 stay in flight across the barrier; HBM latency
// (~900cyc) is covered by ~2 iterations. Race: writer targets (k+2)%4, laggard
// readers hold (k-1)%4 -> distance 3 mod 4, never 0.
__device__ __forceinline__ void gemm128_pipe(
    const __bf16* __restrict__ A, const __bf16* __restrict__ W,
    int m0, int n0, int M, __bf16* At, __bf16* Bt, floatx4 acc[4][4]) {
  const int tid = threadIdx.x, wave = tid >> 6, lane = tid & 63;
  const int l = lane & 15, qd = lane >> 4;
  const int wr = wave >> 1, wc = wave & 1;
  const int srow = lane >> 2, sg = lane & 3;
  const int r0 = wave * 32 + srow, r1 = r0 + 16;
  int gm0 = m0 + r0; if (gm0 >= M) gm0 = M - 1;
  int gm1 = m0 + r1; if (gm1 >= M) gm1 = M - 1;
  const int sw0 = (sg ^ (r0 & 3)) * 8;          // staging XOR swizzle (row&3)
  const __bf16* gA0 = A + (size_t)gm0 * FT + sw0;
  const __bf16* gA1 = A + (size_t)gm1 * FT + sw0;
  const __bf16* gB0 = W + (size_t)(n0 + r0) * FT + sw0;
  const __bf16* gB1 = W + (size_t)(n0 + r1) * FT + sw0;
  const int woff = wave * 1024;
  const int fsw = (qd ^ (l & 3)) * 8;           // fragment-read swizzle

  auto issue = [&](int k, int buf) {
    __bf16* a = At + buf * 4096 + woff;
    __bf16* b = Bt + buf * 4096 + woff;
    async_ld16(gA0 + k * 32, a);
    async_ld16(gA1 + k * 32, a + 512);
    async_ld16(gB0 + k * 32, b);
    async_ld16(gB1 + k * 32, b + 512);
  };
  auto step = [&](int buf) {
    __builtin_amdgcn_s_barrier();
    const __bf16* ab = At + buf * 4096;
    const __bf16* bb = Bt + buf * 4096;
    bf16x8 aF[4], bF[4];
#pragma unroll
    for (int t = 0; t < 4; ++t)
      aF[t] = *(const bf16x8*)(ab + (wr * 64 + t * 16 + l) * 32 + fsw);
#pragma unroll
    for (int u = 0; u < 4; ++u)
      bF[u] = *(const bf16x8*)(bb + (wc * 64 + u * 16 + l) * 32 + fsw);
#pragma unroll
    for (int t = 0; t < 4; ++t)
#pragma unroll
      for (int u = 0; u < 4; ++u)
        acc[t][u] = __builtin_amdgcn_mfma_f32_16x16x32_bf16(aF[t], bF[u], acc[t][u], 0, 0, 0);
  };

  issue(0, 0);
  issue(1, 1);
  int bk = 0;
  for (int k = 0; k < 24; ++k) {               // FT/32 = 24
    if (k + 2 < 24) {
      int bi = bk + 2; if (bi >= 4) bi -= 4;
      issue(k + 2, bi);
      __builtin_amdgcn_s_waitcnt(0x0F78);      // vmcnt(8): tile k landed, k+1/k+2 in flight
    } else if (k == 22) {
      __builtin_amdgcn_s_waitcnt(0x0F74);      // vmcnt(4)
    } else {
      __builtin_amdgcn_s_waitcnt(0x0F70);      // vmcnt(0)
    }
    step(bk);
    bk = (bk + 1) & 3;
  }
}

// ---------------- QKV projection GEMM + bias/scale epilogue ----------------
// Grid swizzle: xcd = u&7; m-tile = ((u>>3)/18)*8 + xcd; n fastest -> A-tile L2-hot.
// Q pre-scaled by 0.125*log2e.
__global__ __launch_bounds__(256) void qkv_gemm128(
    const __bf16* __restrict__ tokens, const __bf16* __restrict__ qkvw,
    const float* __restrict__ qbias, const float* __restrict__ vbias,
    __bf16* __restrict__ Qb, __bf16* __restrict__ Kc, __bf16* __restrict__ Vc) {
  __shared__ __bf16 At[4 * 4096], Bt[4 * 4096];   // 64 KB
  const int u0 = blockIdx.x;
  const int c = u0 & 7, q0 = u0 >> 3;
  const int mi = (q0 / 18) * 8 + c, ni = q0 % 18;
  if (mi >= 65) return;
  const int m0 = mi * 128, n0 = ni * 128;
  const int tid = threadIdx.x, wave = tid >> 6, lane = tid & 63;
  const int l = lane & 15, qd = lane >> 4;
  const int wr = wave >> 1, wc = wave & 1;
  floatx4 acc[4][4];
#pragma unroll
  for (int t = 0; t < 4; ++t)
#pragma unroll
    for (int u = 0; u < 4; ++u) acc[t][u] = (floatx4){0.f, 0.f, 0.f, 0.f};
  gemm128_pipe(tokens, qkvw, m0, n0, MROWS, At, Bt, acc);

  const int which = (n0 / FT);
  const int nrem0 = n0 - which * FT;
#pragma unroll
  for (int u = 0; u < 4; ++u) {
    const int rem = nrem0 + wc * 64 + u * 16 + l;
    const int h = rem >> 6, f = rem & 63;
    const float qb = (which == 0) ? qbias[h * 64 + f] : 0.f;
    const float vb = (which == 2) ? vbias[h * 64 + f] : 0.f;
#pragma unroll
    for (int t = 0; t < 4; ++t) {
#pragma unroll
      for (int r = 0; r < 4; ++r) {
        const int gm = m0 + wr * 64 + t * 16 + qd * 4 + r;
        if (gm >= MROWS) continue;
        const int b = gm / NTOK;
        const int tok = gm - b * NTOK;
        const size_t bh = (size_t)(b * NH + h);
        float v = acc[t][u][r];
        if (which == 0) {
          Qb[(bh * NPAD2 + tok) * 64 + f] = (__bf16)((v + qb) * (0.125f * LOG2E));
        } else if (which == 1) {
          // Kc 32-tok chunks: [bh][tok>>5][dg=f>>3][tok&31][f&7]
          const size_t e = ((size_t)(bh * CH2 + (tok >> 5))) * 2048 +
                           (((f >> 3) * 32 + (tok & 31)) << 3) + (f & 7);
          Kc[e] = (__bf16)v;
        } else {
          // Vc 32-tok chunks: [bh][tok>>5][tg=(tok>>3)&3][f][tok&7]
          const size_t e = ((size_t)(bh * CH2 + (tok >> 5))) * 2048 +
                           (((((tok >> 3) & 3) * 64 + f)) << 3) + (tok & 7);
          Vc[e] = (__bf16)(v + vb);
        }
      }
    }
  }
}

// ---------------- output projection GEMM + bias (fp32 out), same swizzle NB=6 ----------------
__global__ __launch_bounds__(256) void proj_gemm128(
    const __bf16* __restrict__ Ao, const __bf16* __restrict__ projw,
    const float* __restrict__ projb, float* __restrict__ out) {
  __shared__ __bf16 At[4 * 4096], Bt[4 * 4096];
  const int u0 = blockIdx.x;
  const int c = u0 & 7, q0 = u0 >> 3;
  const int mi = (q0 / 6) * 8 + c, ni = q0 % 6;
  if (mi >= 65) return;
  const int m0 = mi * 128, n0 = ni * 128;
  const int tid = threadIdx.x, wave = tid >> 6, lane = tid & 63;
  const int l = lane & 15, qd = lane >> 4;
  const int wr = wave >> 1, wc = wave & 1;
  floatx4 acc[4][4];
#pragma unroll
  for (int t = 0; t < 4; ++t)
#pragma unroll
    for (int u = 0; u < 4; ++u) acc[t][u] = (floatx4){0.f, 0.f, 0.f, 0.f};
  gemm128_pipe(Ao, projw, m0, n0, MROWS, At, Bt, acc);
#pragma unroll
  for (int u = 0; u < 4; ++u) {
    const int gn = n0 + wc * 64 + u * 16 + l;
    const float pb = projb[gn];
#pragma unroll
    for (int t = 0; t < 4; ++t)
#pragma unroll
      for (int r = 0; r < 4; ++r) {
        const int gm = m0 + wr * 64 + t * 16 + qd * 4 + r;
        if (gm < MROWS) out[(size_t)gm * FT + gn] = acc[t][u][r] + pb;
      }
  }
}

// ---------------- pipelined flash attention: 64 Q-rows / 2-wave block, depth-2 ----------------
// 32-token chunks; 4 rotating LDS buffer sets (wave0 stages K, wave1 stages V);
// bias held in 3-deep rolling regs; uniform 6 VMEM issues/iter (index-clamped dups at
// the tail) so the wait is a constant vmcnt(12) = chunks c+1,c+2 in flight.
// S^T = K.Q^T (32x32x16); P = exp2(S + bias') [log2e pre-folded]; O^T = V^T.P^T.
// Pad tokens carry bias -1e30 -> exp2()==0, so un-zeroed K/V pad garbage is inert.
__global__ __launch_bounds__(128) void attn_flash(
    const __bf16* __restrict__ Qb, const __bf16* __restrict__ Kc,
    const __bf16* __restrict__ Vc, const __bf16* __restrict__ Bb,
    __bf16* __restrict__ Ao) {
  __shared__ __bf16 Kl[4][2048], Vl[4][2048];   // 32 KB total
  const int bh = blockIdx.x;
  const int rt = blockIdx.y;
  const int h = bh % NH, b = bh / NH;
  const int wave = threadIdx.x >> 6, lane = threadIdx.x & 63;
  const int l31 = lane & 31, hb = lane >> 5;
  const int qt = rt * 2 + wave;
  int qrow = qt * 32 + l31; if (qrow > NTOK - 1) qrow = NTOK - 1;

  // Q fragments (B-operand): B[n=qrow=lane&31][k = dk*16 + hb*8 + i]
  bf16x8 qf[4];
  {
    const __bf16* Qp = Qb + ((size_t)bh * NPAD2 + qrow) * 64 + hb * 8;
#pragma unroll
    for (int d = 0; d < 4; ++d) qf[d] = *(const bf16x8*)(Qp + d * 16);
  }

  floatx16 o0, o1;
#pragma unroll
  for (int j = 0; j < 16; ++j) { o0[j] = 0.f; o1[j] = 0.f; }
  float lsum = 0.f;

  const __bf16* KVg = (wave ? Vc : Kc) + (size_t)bh * CH2 * 2048;
  const __bf16* Bg = Bb + ((size_t)h * NQT + qt) * NTT * 1024 + lane * 16;

  auto issue = [&](int c, int buf) {
    const __bf16* src = KVg + (size_t)c * 2048 + lane * 8;
    __bf16* dst = wave ? Vl[buf] : Kl[buf];
#pragma unroll
    for (int ii = 0; ii < 4; ++ii) async_ld16(src + ii * 512, dst + ii * 512);
  };

  bf16x8 ba[3], bz[3];
  issue(0, 0);
  ba[0] = *(const bf16x8*)(Bg);
  bz[0] = *(const bf16x8*)(Bg + 8);
  issue(1, 1);
  ba[1] = *(const bf16x8*)(Bg + 1024);
  bz[1] = *(const bf16x8*)(Bg + 1024 + 8);
  int buf = 0;
  for (int c = 0; c < CH2; ++c) {
    {
      int cc = c + 2; if (cc > CH2 - 1) cc = CH2 - 1;   // clamped dup issues at tail
      issue(cc, (buf + 2) & 3);
      ba[2] = *(const bf16x8*)(Bg + (size_t)cc * 1024);
      bz[2] = *(const bf16x8*)(Bg + (size_t)cc * 1024 + 8);
      __builtin_amdgcn_s_waitcnt(0x0F7C);   // vmcnt(12): chunk c landed
    }
    __builtin_amdgcn_s_barrier();

    // QK^T: S^T(32 tokens x 32 qrows)
    floatx16 st;
#pragma unroll
    for (int j = 0; j < 16; ++j) st[j] = 0.f;
#pragma unroll
    for (int dk = 0; dk < 4; ++dk) {
      bf16x8 a = *(const bf16x8*)(Kl[buf] + ((dk * 2 + hb) * 32 + l31) * 8);
      st = __builtin_amdgcn_mfma_f32_32x32x16_bf16(a, qf[dk], st, 0, 0, 0);
    }
    // P = exp2(S^T + bias'), accumulate l
    float e[16];
#pragma unroll
    for (int j = 0; j < 16; ++j) {
      const float bj = (float)(j < 8 ? ba[0][j] : bz[0][j - 8]);
      e[j] = __builtin_amdgcn_exp2f(st[j] + bj);
      lsum += e[j];
    }
    int pk[8];
#pragma unroll
    for (int j2 = 0; j2 < 8; ++j2) {
      bf16x2 pr = {(__bf16)e[2 * j2], (__bf16)e[2 * j2 + 1]};
      pk[j2] = __builtin_bit_cast(int, pr);
    }
    // PV: O^T += V^T . P^T (P^T B-frags via xor-32 exchange)
#pragma unroll
    for (int ks = 0; ks < 2; ++ks) {
      const int r01a = pk[4 * ks + 0], r01b = pk[4 * ks + 1];
      const int r23a = pk[4 * ks + 2], r23b = pk[4 * ks + 3];
      const int t01a = __shfl_xor(r01a, 32), t01b = __shfl_xor(r01b, 32);
      const int t23a = __shfl_xor(r23a, 32), t23b = __shfl_xor(r23b, 32);
      intx4 fi;
      fi[0] = hb ? t23a : r01a;
      fi[1] = hb ? t23b : r01b;
      fi[2] = hb ? r23a : t01a;
      fi[3] = hb ? r23b : t01b;
      bf16x8 pb = __builtin_bit_cast(bf16x8, fi);
      bf16x8 va0 = *(const bf16x8*)(Vl[buf] + ((ks * 2 + hb) * 64 + l31) * 8);
      bf16x8 va1 = *(const bf16x8*)(Vl[buf] + ((ks * 2 + hb) * 64 + 32 + l31) * 8);
      o0 = __builtin_amdgcn_mfma_f32_32x32x16_bf16(va0, pb, o0, 0, 0, 0);
      o1 = __builtin_amdgcn_mfma_f32_32x32x16_bf16(va1, pb, o1, 0, 0, 0);
    }
    ba[0] = ba[1]; ba[1] = ba[2];
    bz[0] = bz[1]; bz[1] = bz[2];
    buf = (buf + 1) & 3;
  }
  __builtin_amdgcn_s_waitcnt(0x0F70);   // drain dup in-flight DMA before endpgm

  const float ltot = lsum + __shfl_xor(lsum, 32);
  const float rinv = 1.0f / ltot;
  const int tok = rt * 64 + wave * 32 + l31;
  if (tok < NTOK) {
    __bf16* op = Ao + ((size_t)b * NTOK + tok) * FT + h * 64;
#pragma unroll
    for (int ft = 0; ft < 2; ++ft) {
#pragma unroll
      for (int jg = 0; jg < 4; ++jg) {
        const int f = ft * 32 + jg * 8 + hb * 4;
        __bf16 v4[4];
#pragma unroll
        for (int q = 0; q < 4; ++q) {
          const float ov = ft ? o1[jg * 4 + q] : o0[jg * 4 + q];
          v4[q] = (__bf16)(ov * rinv);
        }
        *(uint2*)(op + f) = *(uint2*)v4;
      }
    }
  }
}

extern "C" void kernel_launch(void* const* d_in, const int* in_sizes, int n_in,
                              void* d_out, int out_size, void* d_ws, size_t ws_size,
                              hipStream_t stream) {
  (void)in_sizes; (void)n_in; (void)out_size; (void)ws_size;
  const float* tokens = (const float*)d_in[0];
  const float* qkvw   = (const float*)d_in[1];
  const float* qbias  = (const float*)d_in[2];
  const float* vbias  = (const float*)d_in[3];
  const float* table  = (const float*)d_in[4];
  const float* projw  = (const float*)d_in[5];
  const float* projb  = (const float*)d_in[6];
  const int*   rpidx  = (const int*)d_in[7];
  float* out = (float*)d_out;
  char* ws = (char*)d_ws;

  const size_t QB2 = (size_t)B_ * NH * NPAD2 * 64 * 2;        // 13,369,344 B
  const size_t BBT = (size_t)NH * NQT * NTT * 1024 * 2;       // 30,081,024 B
  const size_t AOB = (size_t)MROWS * FT * 2;                  // 12,595,200 B
  const size_t WQB = (size_t)3 * FT * FT * 2;
  __bf16* Qb = (__bf16*)(ws);
  __bf16* Kc = (__bf16*)(ws + QB2);
  __bf16* Vc = (__bf16*)(ws + 2 * QB2);
  __bf16* Bb = (__bf16*)(ws + 3 * QB2);
  __bf16* Tb = (__bf16*)(ws + 3 * QB2 + BBT);  // tokens bf16; Ao aliases (dead after qkv)
  __bf16* Ao = Tb;
  __bf16* Wq = (__bf16*)(ws + 3 * QB2 + BBT + AOB);
  __bf16* Wp = (__bf16*)(ws + 3 * QB2 + BBT + AOB + WQB);
  // total ~87.5 MB

  const int n0 = MROWS * FT / 4, n1 = 3 * FT * FT / 4, n2 = FT * FT / 4;
  cvt3_bf16<<<(n0 + n1 + n2 + 255) / 256, 256, 0, stream>>>(
      tokens, Tb, n0, qkvw, Wq, n1, projw, Wp, n2);
  bias_gather_t<<<dim3(NQT, NTT), 256, 0, stream>>>(rpidx, table, Bb);
  qkv_gemm128<<<8 * 9 * 18, 256, 0, stream>>>(Tb, Wq, qbias, vbias, Qb, Kc, Vc);
  attn_flash<<<dim3(B_ * NH, NRT18), 128, 0, stream>>>(Qb, Kc, Vc, Bb, Ao);
  proj_gemm128<<<8 * 9 * 6, 256, 0, stream>>>(Ao, Wp, projb, out);
}